// Round 11
// baseline (116.392 us; speedup 1.0000x reference)
//
#include <hip/hip_runtime.h>

// MetaUpSampler via bf16 MFMA — round 18 (= R17, compile-fixed).
// R17 failed to compile: __builtin_nontemporal_load/store rejects HIP's
//   float4 (HIP_vector_type class); requires native ext_vector_type. Fix:
//   use f32x4 (already defined) for the nontemporal accesses. No other edit.
// R17 theory (stands): R16 null (12 waves = 113.4 vs 113.0) -> meta ~16.4us
//   is NOT issue-limited. xt (18.9MB = 2.36MB/XCD) fits L2, but (1) prep's
//   linear mapping writes tile (n,h,wt) on XCD bb%8 while meta reads it from
//   XCD tau%8 (cross-XCD -> HBM), and (2) prep's 37.7MB streaming x-reads +
//   meta's 27.6MB out-stores evict xt. Package: XCD-matched prep mapping
//   (bijective 8*96*3=2304) + nontemporal x-loads + nontemporal out-stores.
// Predict: meta 16.4 -> ~9-11us, dur 113.4 -> ~105-108, top-5 all-fill.
//   Null (>=112) refutes the L2-retention hypothesis.
// Workspace: lwb @ 0 (55KB), xt @ +64KB (18.9MB).

#define HH   192
#define WWD  192
#define SS   4
#define OC   3
#define PO   48
#define HID  256
#define W2LD 1728
#define BUFS 21120   // shorts per xlds buffer: 5*66*64

typedef short  bf16x8 __attribute__((ext_vector_type(8)));
typedef float  f32x4  __attribute__((ext_vector_type(4)));

static __device__ __forceinline__ short f2bf(float f) {
    unsigned u = __float_as_uint(f);
    unsigned r = (u + 0x7fffu + ((u >> 16) & 1u)) >> 16;   // RNE
    return (short)r;
}

static __device__ __forceinline__ void pin(bf16x8& v) {
    asm volatile("" : "+v"(v));    // force VGPR residency; block load sinking
}

// ---------------- Stage A (fused): MLP -> weights  +  x -> NHWC bf16 -------
__global__ __launch_bounds__(256) void prep_kernel(
        const float* __restrict__ x,
        const float* __restrict__ W1, const float* __restrict__ b1,
        const float* __restrict__ W2, const float* __restrict__ b2,
        short* __restrict__ lwb, short* __restrict__ xt) {
    const int b = blockIdx.x;
    const int t = threadIdx.x;
    if (b < 112) {
        __shared__ float hlds[HID];
        const int p = b / 7;
        {
            const float pi = (float)(p >> 2) * 0.25f;
            const float pj = (float)(p & 3) * 0.25f;
            const float v = 0.25f * W1[t] + pi * W1[HID + t] + pj * W1[2 * HID + t]
                          + b1[t];
            hlds[t] = v > 0.f ? v : 0.f;
        }
        __syncthreads();
        const int col = (b % 7) * 256 + t;   // 0..1791 (guard at 1728)
        if (col < W2LD) {
            float a = 0.f;
#pragma unroll 32
            for (int hh = 0; hh < HID; ++hh)
                a += hlds[hh] * W2[hh * W2LD + col];   // coalesced 4B + LDS bcast
            const int o = col % 3, kc = col / 3;
            const int tap = kc % 9, c = kc / 9;
            lwb[(tap * PO + p * 3 + o) * 64 + c] = f2bf(a + b2[col]);
        }
    } else {
        __shared__ short tl[64][72];         // [w][c], +8 pad vs bank stride
        // XCD-matched decode: this block runs on XCD bb&7 (112%8==0); give it
        // a row-tile of a meta-tile tau owned by the SAME XCD (tau/96 == bb&7)
        // so meta's xt reads are own-L2 hits.
        const int bb  = b - 112;             // 0..2303
        const int k8  = bb & 7;              // XCD
        const int idx = bb >> 3;             // 0..287
        const int tau = 96 * k8 + idx / 3;   // main consumer meta-tile
        const int hs  = idx % 3;
        const int n   = tau / 192;
        const int rem = tau % 192;
        const int wt  = rem / 64;
        const int h   = (rem % 64) * 3 + hs;
        const int w0  = wt * 64;
#pragma unroll
        for (int i = 0; i < 4; ++i) {
            const int idx2 = i * 256 + t;    // 0..1023
            const int c    = idx2 >> 4;      // channel 0..63
            const int j4   = idx2 & 15;      // float4 within 64 w
            // non-temporal: streaming read, don't evict xt from L2
            const f32x4 v = __builtin_nontemporal_load(
                reinterpret_cast<const f32x4*>(
                    &x[(((size_t)(n * 64 + c)) * HH + h) * WWD + w0 + j4 * 4]));
            tl[j4 * 4 + 0][c] = f2bf(v[0]);
            tl[j4 * 4 + 1][c] = f2bf(v[1]);
            tl[j4 * 4 + 2][c] = f2bf(v[2]);
            tl[j4 * 4 + 3][c] = f2bf(v[3]);
        }
        __syncthreads();
        const int w  = t >> 2;
        const int c0 = (t & 3) * 16;
        short* dst = &xt[(((size_t)n * HH + h) * WWD + w0 + w) * 64 + c0];
        *(bf16x8*)&dst[0] = *(const bf16x8*)&tl[w][c0];
        *(bf16x8*)&dst[8] = *(const bf16x8*)&tl[w][c0 + 8];
    }
}

// ---------------- Stage B: persistent pipelined MFMA conv, 12 waves --------
__global__ __launch_bounds__(768, 1) void meta_up_mfma(
        const short* __restrict__ xt, const short* __restrict__ lwb,
        float* __restrict__ out) {
    // 2 xlds buffers + separate obuf: 84,480 + 37,440 = 121,920 B.
    __shared__ __align__(16) short smem[2 * BUFS + 18720];
    float* obuf = (float*)&smem[2 * BUFS];

    const int xcd = blockIdx.x & 7;       // HW: block b -> XCD b%8
    const int ii  = blockIdx.x >> 3;      // 0..31 within XCD
    const int tid = threadIdx.x;
    const int lane = tid & 63;
    const int wvw  = tid >> 6;            // wave 0..11
    const int wv   = wvw % 3;             // po-tile
    const int mt   = wvw / 3;             // m-tile (one per wave)
    const int quad = lane >> 4, l15 = lane & 15;

    // B fragments: tile-invariant -> load all 18 once, pin to VGPRs.
    bf16x8 Bf[18];
#pragma unroll
    for (int tap = 0; tap < 9; ++tap)
#pragma unroll
        for (int kc2 = 0; kc2 < 2; ++kc2)
            Bf[tap * 2 + kc2] = *(const bf16x8*)
                &lwb[(tap * PO + wv * 16 + l15) * 64 + kc2 * 32 + quad * 8];
#pragma unroll
    for (int i = 0; i < 18; ++i) pin(Bf[i]);

    // Tile decode: tau = 96*xcd + 3*ii + t (consecutive hg -> L2-warm overlap)
    int n_c, h0_c, w0_c;
    {
        const int tau = 96 * xcd + 3 * ii;
        n_c = tau / 192;
        const int rem = tau % 192;
        w0_c = (rem / 64) * 64;
        h0_c = (rem % 64) * 3;
    }

    const bf16x8 z = {0, 0, 0, 0, 0, 0, 0, 0};
    bf16x8 sv[4];                          // 2640 items / 768 threads -> k<4

    // ---- prologue: stage tile 0 into buf0 ---------------------------------
#pragma unroll
    for (int k = 0; k < 4; ++k) {
        const int item = k * 768 + tid;
        const int r  = item / 528;
        const int rm = item - r * 528;
        const int j  = rm >> 3, cb = rm & 7;
        const int gr = h0_c - 1 + r, gc = w0_c - 1 + j;
        const bool ok = (item < 2640) && ((unsigned)gr < (unsigned)HH) &&
                        ((unsigned)gc < (unsigned)WWD);
        sv[k] = ok ? *(const bf16x8*)
            &xt[((size_t)(n_c * HH + gr) * WWD + gc) * 64 + cb * 8] : z;
    }
#pragma unroll
    for (int k = 0; k < 4; ++k) {
        const int item = k * 768 + tid;
        if (item < 2640) {
            const int r  = item / 528;
            const int rm = item - r * 528;
            const int j  = rm >> 3, cb = rm & 7;
            *(bf16x8*)&smem[(r * 66 + j) * 64 + ((cb ^ (j & 7)) << 3)] = sv[k];
        }
    }
    __syncthreads();

    for (int t = 0; t < 3; ++t) {
        int n_n = n_c, h0_n = h0_c, w0_n = w0_c;
        if (t < 2) {
            // decode tile t+1 and ISSUE its loads (hide under MFMA + stores)
            const int tau = 96 * xcd + 3 * ii + t + 1;
            n_n = tau / 192;
            const int rem = tau % 192;
            w0_n = (rem / 64) * 64;
            h0_n = (rem % 64) * 3;
#pragma unroll
            for (int k = 0; k < 4; ++k) {
                const int item = k * 768 + tid;
                const int r  = item / 528;
                const int rm = item - r * 528;
                const int j  = rm >> 3, cb = rm & 7;
                const int gr = h0_n - 1 + r, gc = w0_n - 1 + j;
                const bool ok = (item < 2640) && ((unsigned)gr < (unsigned)HH) &&
                                ((unsigned)gc < (unsigned)WWD);
                sv[k] = ok ? *(const bf16x8*)
                    &xt[((size_t)(n_n * HH + gr) * WWD + gc) * 64 + cb * 8] : z;
            }
        }

        // ---- MFMA phase on buffer t&1: 30 ds_reads, 54 MFMAs per wave -----
        const short* __restrict__ xb = &smem[(t & 1) * BUFS];
        f32x4 acc[3];
#pragma unroll
        for (int ih = 0; ih < 3; ++ih) acc[ih] = (f32x4){0.f, 0.f, 0.f, 0.f};

#pragma unroll
        for (int b = 0; b < 6; ++b) {
            const int dj = b >> 1, kc2 = b & 1;
            const int col = mt * 16 + l15 + dj;      // 0..65
            const int blk = (kc2 * 4 + quad) ^ (col & 7);
#pragma unroll
            for (int r = 0; r < 5; ++r) {
                bf16x8 a = *(const bf16x8*)&xb[(r * 66 + col) * 64 + (blk << 3)];
#pragma unroll
                for (int di = 0; di < 3; ++di) {
                    const int ih = r - di;
                    if (ih >= 0 && ih < 3)
                        acc[ih] = __builtin_amdgcn_mfma_f32_16x16x32_bf16(
                            a, Bf[(di * 3 + dj) * 2 + kc2], acc[ih], 0, 0, 0);
                }
            }
        }

        // ---- epilogue: D -> obuf (separate LDS region) --------------------
        {
            const int po = wv * 16 + l15;
            const int o  = po % 3;
            const int p  = po / 3;
            const int si = p >> 2, sj = p & 3;
            const int osi = o * 4 + si;
#pragma unroll
            for (int ih = 0; ih < 3; ++ih)
#pragma unroll
                for (int r4 = 0; r4 < 4; ++r4) {
                    const int wl = mt * 16 + quad * 4 + r4;
                    obuf[(ih * 12 + osi) * 260 + wl * 4 + sj] = acc[ih][r4];
                }
        }
        __syncthreads();                   // obuf visible; xlds(t) reads done

        // ---- coalesced non-temporal out stores: 1 f32x4 / thread / ih -----
#pragma unroll
        for (int ih = 0; ih < 3; ++ih) {
            const int osi = tid >> 6;      // 0..11
            const int c4  = tid & 63;
            const int o = osi >> 2, si = osi & 3;
            const int hh = h0_c + ih;
            const size_t base =
                ((size_t)(n_c * OC + o) * (SS * HH) + (size_t)(SS * hh + si))
                    * (SS * WWD) + (size_t)(4 * w0_c) + c4 * 4;
            // non-temporal: out is never re-read; don't evict xt from L2
            __builtin_nontemporal_store(
                *(const f32x4*)&obuf[(ih * 12 + osi) * 260 + c4 * 4],
                reinterpret_cast<f32x4*>(&out[base]));
        }

        if (t < 2) {
            // first use of sv -> vmcnt wait lands HERE, after MFMA + stores
#pragma unroll
            for (int k = 0; k < 4; ++k) {
                const int item = k * 768 + tid;
                if (item < 2640) {
                    const int r  = item / 528;
                    const int rm = item - r * 528;
                    const int j  = rm >> 3, cb = rm & 7;
                    *(bf16x8*)&smem[((t + 1) & 1) * BUFS +
                        (r * 66 + j) * 64 + ((cb ^ (j & 7)) << 3)] = sv[k];
                }
            }
            __syncthreads();               // buf(t+1) visible before MFMA(t+1)
            n_c = n_n; h0_c = h0_n; w0_c = w0_n;
        }
    }
}

extern "C" void kernel_launch(void* const* d_in, const int* in_sizes, int n_in,
                              void* d_out, int out_size, void* d_ws, size_t ws_size,
                              hipStream_t stream) {
    const float* x  = (const float*)d_in[0];
    const float* W1 = (const float*)d_in[1];
    const float* b1 = (const float*)d_in[2];
    const float* W2 = (const float*)d_in[3];
    const float* b2 = (const float*)d_in[4];
    float* out = (float*)d_out;
    short* lwb = (short*)d_ws;                  // 27,648 bf16 = 55 KB
    short* xt  = (short*)d_ws + 32768;          // NHWC bf16 x, 18.9 MB

    prep_kernel<<<112 + 4 * HH * 3, 256, 0, stream>>>(x, W1, b1, W2, b2, lwb, xt);
    meta_up_mfma<<<256, 768, 0, stream>>>(xt, lwb, out);
}

// Round 12
// 114.772 us; speedup vs baseline: 1.0141x; 1.0141x over previous
//
#include <hip/hip_runtime.h>

// MetaUpSampler via bf16 MFMA — round 19 (= R16 meta + 4-row pipelined prep).
// R18 post-mortem: L2-residency package REFUTED (116.4 vs 113.4) — reverted.
// Ledger audit: R15's DIRECT meta measurement (43.5us) gives F ~67.5, which
//   back-propagates prep ~25-27us (not 13!) for 56.6MB = 2.2TB/s, 2.8x over
//   floor. Cause: 2304 TINY transpose blocks (4 float4/thread, ~2 VMEM deep)
//   -> unamortized load latency + dispatch ramp. Same short-block disease
//   meta had pre-R14.
// R19 fix (prep only; meta = validated R16 byte-for-byte):
//   transpose block = 4 consecutive h rows (576 blocks), software-pipelined:
//   issue row hh+1 loads BEFORE transposing row hh; double-buffered tl
//   (2x64x72 shorts); 1 barrier/row (buffer alternation removes the 2nd).
//   8+ loads in flight/thread; dispatch /4; consecutive-h segments 768B
//   apart per c-plane (page locality). lw part unchanged.
// Predict: prep~25 branch -> dur ~101-105; prep~13 branch -> ~109-111.
//   >=112 = both kernels at structural floor -> declare ROOFLINE next.
// Workspace: lwb @ 0 (55KB), xt @ +64KB (18.9MB).

#define HH   192
#define WWD  192
#define SS   4
#define OC   3
#define PO   48
#define HID  256
#define W2LD 1728
#define BUFS 21120   // shorts per xlds buffer: 5*66*64

typedef short  bf16x8 __attribute__((ext_vector_type(8)));
typedef float  f32x4  __attribute__((ext_vector_type(4)));

static __device__ __forceinline__ short f2bf(float f) {
    unsigned u = __float_as_uint(f);
    unsigned r = (u + 0x7fffu + ((u >> 16) & 1u)) >> 16;   // RNE
    return (short)r;
}

static __device__ __forceinline__ void pin(bf16x8& v) {
    asm volatile("" : "+v"(v));    // force VGPR residency; block load sinking
}

// ---------------- Stage A (fused): MLP -> weights  +  x -> NHWC bf16 -------
// Blocks 0..111: lw MLP. Blocks 112..687: transpose FOUR consecutive (n,h)
// rows x 64w from NCHW f32 to NHWC bf16, software-pipelined across rows.
__global__ __launch_bounds__(256) void prep_kernel(
        const float* __restrict__ x,
        const float* __restrict__ W1, const float* __restrict__ b1,
        const float* __restrict__ W2, const float* __restrict__ b2,
        short* __restrict__ lwb, short* __restrict__ xt) {
    const int b = blockIdx.x;
    const int t = threadIdx.x;
    if (b < 112) {
        __shared__ float hlds[HID];
        const int p = b / 7;
        {
            const float pi = (float)(p >> 2) * 0.25f;
            const float pj = (float)(p & 3) * 0.25f;
            const float v = 0.25f * W1[t] + pi * W1[HID + t] + pj * W1[2 * HID + t]
                          + b1[t];
            hlds[t] = v > 0.f ? v : 0.f;
        }
        __syncthreads();
        const int col = (b % 7) * 256 + t;   // 0..1791 (guard at 1728)
        if (col < W2LD) {
            float a = 0.f;
#pragma unroll 32
            for (int hh = 0; hh < HID; ++hh)
                a += hlds[hh] * W2[hh * W2LD + col];   // coalesced 4B + LDS bcast
            const int o = col % 3, kc = col / 3;
            const int tap = kc % 9, c = kc / 9;
            lwb[(tap * PO + p * 3 + o) * 64 + c] = f2bf(a + b2[col]);
        }
    } else {
        __shared__ short tl[2][64][72];      // double-buffered [w][c], +8 pad
        const int bb = b - 112;              // 0..575
        const int wt = bb % 3;
        const int g  = (bb / 3) % 48;        // 4-row group
        const int n  = bb / 144;
        const int w0 = wt * 64;
        const int c  = t >> 2;               // this thread's channel (load role)
        const int q4 = (t & 3) * 4;          // 4 float4s per row: j4 = q4..q4+3
        const float* __restrict__ xrow =
            &x[(((size_t)(n * 64 + c)) * HH + g * 4) * WWD + w0];
        const int wr  = t >> 2;              // store-role w (same arithmetic)
        const int c0  = (t & 3) * 16;

        float4 cur[4], nxt[4];
#pragma unroll
        for (int q = 0; q < 4; ++q)          // row 0 loads
            cur[q] = *(const float4*)&xrow[(q4 + q) * 4];

#pragma unroll
        for (int hh = 0; hh < 4; ++hh) {
            if (hh < 3) {                    // issue row hh+1 BEFORE transposing
#pragma unroll
                for (int q = 0; q < 4; ++q)
                    nxt[q] = *(const float4*)&xrow[(size_t)(hh + 1) * WWD + (q4 + q) * 4];
            }
            // transpose cur -> tl[hh&1]
#pragma unroll
            for (int q = 0; q < 4; ++q) {
                const int j = (q4 + q) * 4;
                tl[hh & 1][j + 0][c] = f2bf(cur[q].x);
                tl[hh & 1][j + 1][c] = f2bf(cur[q].y);
                tl[hh & 1][j + 2][c] = f2bf(cur[q].z);
                tl[hh & 1][j + 3][c] = f2bf(cur[q].w);
            }
            __syncthreads();                 // tile visible (1 barrier/row)
            {
                const int h = g * 4 + hh;
                short* dst = &xt[(((size_t)n * HH + h) * WWD + w0 + wr) * 64 + c0];
                *(bf16x8*)&dst[0] = *(const bf16x8*)&tl[hh & 1][wr][c0];
                *(bf16x8*)&dst[8] = *(const bf16x8*)&tl[hh & 1][wr][c0 + 8];
            }
            // next write goes to the OTHER buffer: no second barrier needed
#pragma unroll
            for (int q = 0; q < 4; ++q) cur[q] = nxt[q];
        }
    }
}

// ---------------- Stage B: persistent pipelined MFMA conv, 12 waves --------
// (validated R16 kernel, unchanged)
__global__ __launch_bounds__(768, 1) void meta_up_mfma(
        const short* __restrict__ xt, const short* __restrict__ lwb,
        float* __restrict__ out) {
    // 2 xlds buffers + separate obuf: 84,480 + 37,440 = 121,920 B.
    __shared__ __align__(16) short smem[2 * BUFS + 18720];
    float* obuf = (float*)&smem[2 * BUFS];

    const int xcd = blockIdx.x & 7;       // HW: block b -> XCD b%8
    const int ii  = blockIdx.x >> 3;      // 0..31 within XCD
    const int tid = threadIdx.x;
    const int lane = tid & 63;
    const int wvw  = tid >> 6;            // wave 0..11
    const int wv   = wvw % 3;             // po-tile
    const int mt   = wvw / 3;             // m-tile (one per wave)
    const int quad = lane >> 4, l15 = lane & 15;

    // B fragments: tile-invariant -> load all 18 once, pin to VGPRs.
    bf16x8 Bf[18];
#pragma unroll
    for (int tap = 0; tap < 9; ++tap)
#pragma unroll
        for (int kc2 = 0; kc2 < 2; ++kc2)
            Bf[tap * 2 + kc2] = *(const bf16x8*)
                &lwb[(tap * PO + wv * 16 + l15) * 64 + kc2 * 32 + quad * 8];
#pragma unroll
    for (int i = 0; i < 18; ++i) pin(Bf[i]);

    // Tile decode: tau = 96*xcd + 3*ii + t (consecutive hg -> L2-warm overlap)
    int n_c, h0_c, w0_c;
    {
        const int tau = 96 * xcd + 3 * ii;
        n_c = tau / 192;
        const int rem = tau % 192;
        w0_c = (rem / 64) * 64;
        h0_c = (rem % 64) * 3;
    }

    const bf16x8 z = {0, 0, 0, 0, 0, 0, 0, 0};
    bf16x8 sv[4];                          // 2640 items / 768 threads -> k<4

    // ---- prologue: stage tile 0 into buf0 ---------------------------------
#pragma unroll
    for (int k = 0; k < 4; ++k) {
        const int item = k * 768 + tid;
        const int r  = item / 528;
        const int rm = item - r * 528;
        const int j  = rm >> 3, cb = rm & 7;
        const int gr = h0_c - 1 + r, gc = w0_c - 1 + j;
        const bool ok = (item < 2640) && ((unsigned)gr < (unsigned)HH) &&
                        ((unsigned)gc < (unsigned)WWD);
        sv[k] = ok ? *(const bf16x8*)
            &xt[((size_t)(n_c * HH + gr) * WWD + gc) * 64 + cb * 8] : z;
    }
#pragma unroll
    for (int k = 0; k < 4; ++k) {
        const int item = k * 768 + tid;
        if (item < 2640) {
            const int r  = item / 528;
            const int rm = item - r * 528;
            const int j  = rm >> 3, cb = rm & 7;
            *(bf16x8*)&smem[(r * 66 + j) * 64 + ((cb ^ (j & 7)) << 3)] = sv[k];
        }
    }
    __syncthreads();

    for (int t = 0; t < 3; ++t) {
        int n_n = n_c, h0_n = h0_c, w0_n = w0_c;
        if (t < 2) {
            // decode tile t+1 and ISSUE its loads (hide under MFMA + stores)
            const int tau = 96 * xcd + 3 * ii + t + 1;
            n_n = tau / 192;
            const int rem = tau % 192;
            w0_n = (rem / 64) * 64;
            h0_n = (rem % 64) * 3;
#pragma unroll
            for (int k = 0; k < 4; ++k) {
                const int item = k * 768 + tid;
                const int r  = item / 528;
                const int rm = item - r * 528;
                const int j  = rm >> 3, cb = rm & 7;
                const int gr = h0_n - 1 + r, gc = w0_n - 1 + j;
                const bool ok = (item < 2640) && ((unsigned)gr < (unsigned)HH) &&
                                ((unsigned)gc < (unsigned)WWD);
                sv[k] = ok ? *(const bf16x8*)
                    &xt[((size_t)(n_n * HH + gr) * WWD + gc) * 64 + cb * 8] : z;
            }
        }

        // ---- MFMA phase on buffer t&1: 30 ds_reads, 54 MFMAs per wave -----
        const short* __restrict__ xb = &smem[(t & 1) * BUFS];
        f32x4 acc[3];
#pragma unroll
        for (int ih = 0; ih < 3; ++ih) acc[ih] = (f32x4){0.f, 0.f, 0.f, 0.f};

#pragma unroll
        for (int b = 0; b < 6; ++b) {
            const int dj = b >> 1, kc2 = b & 1;
            const int col = mt * 16 + l15 + dj;      // 0..65
            const int blk = (kc2 * 4 + quad) ^ (col & 7);
#pragma unroll
            for (int r = 0; r < 5; ++r) {
                bf16x8 a = *(const bf16x8*)&xb[(r * 66 + col) * 64 + (blk << 3)];
#pragma unroll
                for (int di = 0; di < 3; ++di) {
                    const int ih = r - di;
                    if (ih >= 0 && ih < 3)
                        acc[ih] = __builtin_amdgcn_mfma_f32_16x16x32_bf16(
                            a, Bf[(di * 3 + dj) * 2 + kc2], acc[ih], 0, 0, 0);
                }
            }
        }

        // ---- epilogue: D -> obuf (separate LDS region) --------------------
        {
            const int po = wv * 16 + l15;
            const int o  = po % 3;
            const int p  = po / 3;
            const int si = p >> 2, sj = p & 3;
            const int osi = o * 4 + si;
#pragma unroll
            for (int ih = 0; ih < 3; ++ih)
#pragma unroll
                for (int r4 = 0; r4 < 4; ++r4) {
                    const int wl = mt * 16 + quad * 4 + r4;
                    obuf[(ih * 12 + osi) * 260 + wl * 4 + sj] = acc[ih][r4];
                }
        }
        __syncthreads();                   // obuf visible; xlds(t) reads done

        // ---- coalesced out stores: exactly 1 float4 / thread / ih ---------
#pragma unroll
        for (int ih = 0; ih < 3; ++ih) {
            const int osi = tid >> 6;      // 0..11
            const int c4  = tid & 63;
            const int o = osi >> 2, si = osi & 3;
            const int hh = h0_c + ih;
            const size_t base =
                ((size_t)(n_c * OC + o) * (SS * HH) + (size_t)(SS * hh + si))
                    * (SS * WWD) + (size_t)(4 * w0_c) + c4 * 4;
            *(float4*)&out[base] =
                *(const float4*)&obuf[(ih * 12 + osi) * 260 + c4 * 4];
        }

        if (t < 2) {
            // first use of sv -> vmcnt wait lands HERE, after MFMA + stores
#pragma unroll
            for (int k = 0; k < 4; ++k) {
                const int item = k * 768 + tid;
                if (item < 2640) {
                    const int r  = item / 528;
                    const int rm = item - r * 528;
                    const int j  = rm >> 3, cb = rm & 7;
                    *(bf16x8*)&smem[((t + 1) & 1) * BUFS +
                        (r * 66 + j) * 64 + ((cb ^ (j & 7)) << 3)] = sv[k];
                }
            }
            __syncthreads();               // buf(t+1) visible before MFMA(t+1)
            n_c = n_n; h0_c = h0_n; w0_c = w0_n;
        }
    }
}

extern "C" void kernel_launch(void* const* d_in, const int* in_sizes, int n_in,
                              void* d_out, int out_size, void* d_ws, size_t ws_size,
                              hipStream_t stream) {
    const float* x  = (const float*)d_in[0];
    const float* W1 = (const float*)d_in[1];
    const float* b1 = (const float*)d_in[2];
    const float* W2 = (const float*)d_in[3];
    const float* b2 = (const float*)d_in[4];
    float* out = (float*)d_out;
    short* lwb = (short*)d_ws;                  // 27,648 bf16 = 55 KB
    short* xt  = (short*)d_ws + 32768;          // NHWC bf16 x, 18.9 MB

    prep_kernel<<<112 + 576, 256, 0, stream>>>(x, W1, b1, W2, b2, lwb, xt);
    meta_up_mfma<<<256, 768, 0, stream>>>(xt, lwb, out);
}

// Round 13
// 111.911 us; speedup vs baseline: 1.0400x; 1.0256x over previous
//
#include <hip/hip_runtime.h>

// MetaUpSampler via bf16 MFMA — round 20 (= exact revert to R14, session best
// at 113.0us). R19 (4-row prep) was null (114.8) -> pre-committed floor
// criterion fired. Six levers tried since R13: TLP x2 (null), fused NCHW in
// both regimes (regress), persistent pipeline (WIN -5.6us), 12 waves (null),
// L2-residency package (regress), pipelined prep (null). Remaining total =
// ~84us fixed harness (268MB re-poison fill @ 76-79% HBM peak + memset train)
// + prep ~13 + meta ~16 vs ~17us combined traffic floor.
// This round: revert to best-validated R14 so the final kernel on file is the
// best one. Predict 112-115; then declare ROOFLINE.
// Workspace: lwb @ 0 (55KB), xt @ +64KB (18.9MB).

#define HH   192
#define WWD  192
#define SS   4
#define OC   3
#define PO   48
#define HID  256
#define W2LD 1728
#define BUFS 21120   // shorts per xlds buffer: 5*66*64

typedef short  bf16x8 __attribute__((ext_vector_type(8)));
typedef float  f32x4  __attribute__((ext_vector_type(4)));

static __device__ __forceinline__ short f2bf(float f) {
    unsigned u = __float_as_uint(f);
    unsigned r = (u + 0x7fffu + ((u >> 16) & 1u)) >> 16;   // RNE
    return (short)r;
}

static __device__ __forceinline__ void pin(bf16x8& v) {
    asm volatile("" : "+v"(v));    // force VGPR residency; block load sinking
}

// ---------------- Stage A (fused): MLP -> weights  +  x -> NHWC bf16 -------
__global__ __launch_bounds__(256) void prep_kernel(
        const float* __restrict__ x,
        const float* __restrict__ W1, const float* __restrict__ b1,
        const float* __restrict__ W2, const float* __restrict__ b2,
        short* __restrict__ lwb, short* __restrict__ xt) {
    const int b = blockIdx.x;
    const int t = threadIdx.x;
    if (b < 112) {
        __shared__ float hlds[HID];
        const int p = b / 7;
        {
            const float pi = (float)(p >> 2) * 0.25f;
            const float pj = (float)(p & 3) * 0.25f;
            const float v = 0.25f * W1[t] + pi * W1[HID + t] + pj * W1[2 * HID + t]
                          + b1[t];
            hlds[t] = v > 0.f ? v : 0.f;
        }
        __syncthreads();
        const int col = (b % 7) * 256 + t;   // 0..1791 (guard at 1728)
        if (col < W2LD) {
            float a = 0.f;
#pragma unroll 32
            for (int hh = 0; hh < HID; ++hh)
                a += hlds[hh] * W2[hh * W2LD + col];   // coalesced 4B + LDS bcast
            const int o = col % 3, kc = col / 3;
            const int tap = kc % 9, c = kc / 9;
            lwb[(tap * PO + p * 3 + o) * 64 + c] = f2bf(a + b2[col]);
        }
    } else {
        __shared__ short tl[64][72];         // [w][c], +8 pad vs bank stride
        const int bb = b - 112;
        const int wt = bb % 3;
        const int h  = (bb / 3) % HH;
        const int n  = bb / (3 * HH);
        const int w0 = wt * 64;
#pragma unroll
        for (int i = 0; i < 4; ++i) {
            const int idx = i * 256 + t;     // 0..1023
            const int c   = idx >> 4;        // channel 0..63
            const int j4  = idx & 15;        // float4 within 64 w
            const float4 v = *(const float4*)
                &x[(((size_t)(n * 64 + c)) * HH + h) * WWD + w0 + j4 * 4];
            tl[j4 * 4 + 0][c] = f2bf(v.x);
            tl[j4 * 4 + 1][c] = f2bf(v.y);
            tl[j4 * 4 + 2][c] = f2bf(v.z);
            tl[j4 * 4 + 3][c] = f2bf(v.w);
        }
        __syncthreads();
        const int w  = t >> 2;
        const int c0 = (t & 3) * 16;
        short* dst = &xt[(((size_t)n * HH + h) * WWD + w0 + w) * 64 + c0];
        *(bf16x8*)&dst[0] = *(const bf16x8*)&tl[w][c0];
        *(bf16x8*)&dst[8] = *(const bf16x8*)&tl[w][c0 + 8];
    }
}

// ---------------- Stage B: persistent pipelined MFMA dynamic conv ----------
__global__ __launch_bounds__(384) void meta_up_mfma(
        const short* __restrict__ xt, const short* __restrict__ lwb,
        float* __restrict__ out) {
    // 2 xlds buffers + separate obuf: 84,480 + 37,440 = 121,920 B.
    __shared__ __align__(16) short smem[2 * BUFS + 18720];
    float* obuf = (float*)&smem[2 * BUFS];

    const int xcd = blockIdx.x & 7;       // HW: block b -> XCD b%8
    const int ii  = blockIdx.x >> 3;      // 0..31 within XCD
    const int tid = threadIdx.x;
    const int lane = tid & 63;
    const int wv   = (tid >> 6) % 3;      // po-tile
    const int wgq  = (tid >> 6) / 3;      // m-tile half
    const int quad = lane >> 4, l15 = lane & 15;

    // B fragments: tile-invariant -> load all 18 once, pin to VGPRs.
    bf16x8 Bf[18];
#pragma unroll
    for (int tap = 0; tap < 9; ++tap)
#pragma unroll
        for (int kc2 = 0; kc2 < 2; ++kc2)
            Bf[tap * 2 + kc2] = *(const bf16x8*)
                &lwb[(tap * PO + wv * 16 + l15) * 64 + kc2 * 32 + quad * 8];
#pragma unroll
    for (int i = 0; i < 18; ++i) pin(Bf[i]);

    // Tile decode: tau = 96*xcd + 3*ii + t, t = 0..2 (consecutive hg ->
    // tile t+1's rows are L2-warm from tile t's reads).
    int n_c, h0_c, w0_c;                  // current-tile params
    {
        const int tau = 96 * xcd + 3 * ii;
        n_c = tau / 192;
        const int rem = tau % 192;
        w0_c = (rem / 64) * 64;
        h0_c = (rem % 64) * 3;
    }

    const bf16x8 z = {0, 0, 0, 0, 0, 0, 0, 0};
    bf16x8 sv[7];

    // ---- stage-load tile 0 into regs, write buf0, barrier ------------------
#pragma unroll
    for (int k = 0; k < 7; ++k) {
        const int item = k * 384 + tid;
        const int r  = item / 528;
        const int rm = item - r * 528;
        const int j  = rm >> 3, cb = rm & 7;
        const int gr = h0_c - 1 + r, gc = w0_c - 1 + j;
        const bool ok = (item < 2640) && ((unsigned)gr < (unsigned)HH) &&
                        ((unsigned)gc < (unsigned)WWD);
        sv[k] = ok ? *(const bf16x8*)
            &xt[((size_t)(n_c * HH + gr) * WWD + gc) * 64 + cb * 8] : z;
    }
#pragma unroll
    for (int k = 0; k < 7; ++k) {
        const int item = k * 384 + tid;
        if (item < 2640) {
            const int r  = item / 528;
            const int rm = item - r * 528;
            const int j  = rm >> 3, cb = rm & 7;
            *(bf16x8*)&smem[(r * 66 + j) * 64 + ((cb ^ (j & 7)) << 3)] = sv[k];
        }
    }
    __syncthreads();

    for (int t = 0; t < 3; ++t) {
        int n_n = n_c, h0_n = h0_c, w0_n = w0_c;
        if (t < 2) {
            // decode tile t+1 and ISSUE its loads (hide under MFMA+epilogue)
            const int tau = 96 * xcd + 3 * ii + t + 1;
            n_n = tau / 192;
            const int rem = tau % 192;
            w0_n = (rem / 64) * 64;
            h0_n = (rem % 64) * 3;
#pragma unroll
            for (int k = 0; k < 7; ++k) {
                const int item = k * 384 + tid;
                const int r  = item / 528;
                const int rm = item - r * 528;
                const int j  = rm >> 3, cb = rm & 7;
                const int gr = h0_n - 1 + r, gc = w0_n - 1 + j;
                const bool ok = (item < 2640) && ((unsigned)gr < (unsigned)HH) &&
                                ((unsigned)gc < (unsigned)WWD);
                sv[k] = ok ? *(const bf16x8*)
                    &xt[((size_t)(n_n * HH + gr) * WWD + gc) * 64 + cb * 8] : z;
            }
        }

        // ---- MFMA phase on buffer t&1 (validated R12 loop) ----------------
        const short* __restrict__ xb = &smem[(t & 1) * BUFS];
        f32x4 acc[3][2];
#pragma unroll
        for (int ih = 0; ih < 3; ++ih)
#pragma unroll
            for (int mtl = 0; mtl < 2; ++mtl)
                acc[ih][mtl] = (f32x4){0.f, 0.f, 0.f, 0.f};

#pragma unroll
        for (int b = 0; b < 6; ++b) {
            const int dj = b >> 1, kc2 = b & 1;
#pragma unroll
            for (int mtl = 0; mtl < 2; ++mtl) {
                const int mt  = wgq * 2 + mtl;
                const int col = mt * 16 + l15 + dj;      // 0..65
                const int blk = (kc2 * 4 + quad) ^ (col & 7);
#pragma unroll
                for (int r = 0; r < 5; ++r) {
                    bf16x8 a = *(const bf16x8*)&xb[(r * 66 + col) * 64 + (blk << 3)];
#pragma unroll
                    for (int di = 0; di < 3; ++di) {
                        const int ih = r - di;
                        if (ih >= 0 && ih < 3)
                            acc[ih][mtl] = __builtin_amdgcn_mfma_f32_16x16x32_bf16(
                                a, Bf[(di * 3 + dj) * 2 + kc2], acc[ih][mtl], 0, 0, 0);
                    }
                }
            }
        }

        // ---- epilogue: D -> obuf (separate LDS; no clash with xlds) -------
        {
            const int po = wv * 16 + l15;
            const int o  = po % 3;
            const int p  = po / 3;
            const int si = p >> 2, sj = p & 3;
            const int osi = o * 4 + si;
#pragma unroll
            for (int ih = 0; ih < 3; ++ih)
#pragma unroll
                for (int mtl = 0; mtl < 2; ++mtl) {
                    const int mt = wgq * 2 + mtl;
#pragma unroll
                    for (int r4 = 0; r4 < 4; ++r4) {
                        const int wl = mt * 16 + quad * 4 + r4;
                        obuf[(ih * 12 + osi) * 260 + wl * 4 + sj] = acc[ih][mtl][r4];
                    }
                }
        }
        __syncthreads();                   // obuf visible (also drains t's reads)

        // ---- coalesced out stores (overlap next tile's loads in HBM) ------
#pragma unroll
        for (int ih = 0; ih < 3; ++ih)
#pragma unroll
            for (int h2 = 0; h2 < 2; ++h2) {
                const int idx = h2 * 384 + tid;      // 0..767
                const int osi = idx >> 6;            // 0..11
                const int c4  = idx & 63;
                const int o = osi >> 2, si = osi & 3;
                const int hh = h0_c + ih;
                const size_t base =
                    ((size_t)(n_c * OC + o) * (SS * HH) + (size_t)(SS * hh + si))
                        * (SS * WWD) + (size_t)(4 * w0_c) + c4 * 4;
                *(float4*)&out[base] =
                    *(const float4*)&obuf[(ih * 12 + osi) * 260 + c4 * 4];
            }

        if (t < 2) {
            // ds_write tile t+1 into the OTHER buffer (no WAR with MFMA(t))
#pragma unroll
            for (int k = 0; k < 7; ++k) {
                const int item = k * 384 + tid;
                if (item < 2640) {
                    const int r  = item / 528;
                    const int rm = item - r * 528;
                    const int j  = rm >> 3, cb = rm & 7;
                    *(bf16x8*)&smem[((t + 1) & 1) * BUFS +
                        (r * 66 + j) * 64 + ((cb ^ (j & 7)) << 3)] = sv[k];
                }
            }
            __syncthreads();               // buf(t+1) visible before MFMA(t+1)
            n_c = n_n; h0_c = h0_n; w0_c = w0_n;
        }
    }
}

extern "C" void kernel_launch(void* const* d_in, const int* in_sizes, int n_in,
                              void* d_out, int out_size, void* d_ws, size_t ws_size,
                              hipStream_t stream) {
    const float* x  = (const float*)d_in[0];
    const float* W1 = (const float*)d_in[1];
    const float* b1 = (const float*)d_in[2];
    const float* W2 = (const float*)d_in[3];
    const float* b2 = (const float*)d_in[4];
    float* out = (float*)d_out;
    short* lwb = (short*)d_ws;                  // 27,648 bf16 = 55 KB
    short* xt  = (short*)d_ws + 32768;          // NHWC bf16 x, 18.9 MB

    prep_kernel<<<112 + 4 * HH * 3, 256, 0, stream>>>(x, W1, b1, W2, b2, lwb, xt);
    meta_up_mfma<<<256, 384, 0, stream>>>(xt, lwb, out);
}